// Round 7
// baseline (391.733 us; speedup 1.0000x reference)
//
#include <hip/hip_runtime.h>
#include <hip/hip_bf16.h>

// ============================================================================
// AttentionHead (B=8,S=4096,D=1024,DK=64), fp32 in/out — MI355X gfx950
// R7 (= R6 resubmit; bench timed out): register double-buffer prefetch
//     (depth-1) in BOTH hot kernels: proj prefetches next K-step's W
//     fragments; attn prefetches next KV tile's K fragments. Static indexing.
// Precision: split-bf16 (hi+lo) x 3-product MFMA => ~fp32 accuracy.
// K0 splitw : W -> bf16 hi/lo, k-chunked [kb][192][8] layout
// K1 proj   : Q (pre-scaled by dm^-.5*log2e); K/V -> per-tile FRAGMENT layout
// K2 attn   : flash chunk, 1 wave = 32 q rows, KVB=64, 32x32x16 bf16 MFMA,
//             swapped QK^T (S^T in regs), scalar m/l per lane, NO LDS
// K3 combine: merge partial (O,m,l) chunks (exp2 domain)
// ============================================================================

typedef __attribute__((ext_vector_type(8)))  short   short8;
typedef __attribute__((ext_vector_type(4)))  float   f32x4;
typedef __attribute__((ext_vector_type(16))) float   f32x16;
typedef __attribute__((ext_vector_type(4)))  unsigned short ushort4v;

#define DEV static __device__ __forceinline__

constexpr int SEQ    = 4096;
constexpr int DMODEL = 1024;
constexpr int DHEAD  = 64;
// fold d_model^-0.5 AND log2(e) into Q so attn uses exp2 directly
constexpr float QSCALE = 0.03125f * 1.44269504088896340736f;
constexpr float MASK_S = -30000.f;   // masked score (log2 domain), finite
constexpr float M_INIT = -10000.f;   // running-max init; MASK_S - M_INIT << 0

DEV unsigned short f2bf(float x) {           // fp32 -> bf16 RNE
    union { float f; unsigned u; } v; v.f = x;
    unsigned r = v.u + 0x7fffu + ((v.u >> 16) & 1u);
    return (unsigned short)(r >> 16);
}
DEV float bf2f(unsigned short h) {
    union { unsigned u; float f; } v; v.u = ((unsigned)h) << 16;
    return v.f;
}
DEV float asf(unsigned u) { union { unsigned u; float f; } v; v.u = u; return v.f; }
// byte address inside a [rows][64]bf16 tile (pitch 128B) with XOR swizzle
DEV int swz(int row, int off) { return row * 128 + (off ^ ((row & 7) << 4)); }

DEV unsigned cvtpk(float lo, float hi) {     // pack 2 fp32 -> 2 bf16 (lo|hi<<16)
    unsigned r;
    asm("v_cvt_pk_bf16_f32 %0, %1, %2" : "=v"(r) : "v"(lo), "v"(hi));
    return r;
}
DEV short8 mk8(unsigned a, unsigned b, unsigned c, unsigned d) {
    union { unsigned u[4]; short8 s; } x;
    x.u[0] = a; x.u[1] = b; x.u[2] = c; x.u[3] = d; return x.s;
}

// ---------------------------------------------------------------- kernel 0 --
// W -> bf16 hi/lo, layout [kb=k/8][row 0..191][8]  (coalesced frag reads)
__global__ void splitw_kernel(const float* __restrict__ wQ,
                              const float* __restrict__ wK,
                              const float* __restrict__ wV,
                              unsigned short* __restrict__ WHp,
                              unsigned short* __restrict__ WLp)
{
    int t   = blockIdx.x * 256 + threadIdx.x;  // 49152 float4 chunks, exact
    int fl  = t * 4;
    int row = fl >> 10;                        // 0..191 (Q,K,V stacked)
    int k   = fl & 1023;
    const float* src = (row < 64) ? wQ : (row < 128 ? wK : wV);
    float4 v = *(const float4*)(src + (row & 63) * 1024 + k);
    float vv[4] = {v.x, v.y, v.z, v.w};
    ushort4v h, l;
    #pragma unroll
    for (int j = 0; j < 4; j++) {
        unsigned short hh = f2bf(vv[j]);
        h[j] = hh;
        l[j] = f2bf(vv[j] - bf2f(hh));
    }
    size_t u = (size_t)(k >> 3) * 1536 + row * 8 + (k & 7);
    *(ushort4v*)(WHp + u) = h;
    *(ushort4v*)(WLp + u) = l;
}

// ---------------------------------------------------------------- kernel 1 --
// M=32 rows/block, 1024 blocks (4/CU), 4 waves; wave w owns cols [48w,48w+48).
// K-step 64, 16 iters. W frags reg-dbuf (prefetch kt+1); x dbuf in LDS (16KB).
__global__ __launch_bounds__(256, 4)
void proj_kernel(const float* __restrict__ x,
                 const unsigned short* __restrict__ WHp,
                 const unsigned short* __restrict__ WLp,
                 unsigned short* __restrict__ QH, unsigned short* __restrict__ QL,
                 unsigned short* __restrict__ KV)
{
    __shared__ unsigned char sm[16384];        // dbuf: [cur][hi 4KB | lo 4KB]
    const int tid  = threadIdx.x;
    const int lane = tid & 63;
    const int w    = tid >> 6;
    const int m0   = blockIdx.x * 32;          // global row base (b*4096+s0)
    const int b    = m0 >> 12;
    const int s0   = m0 & 4095;
    const int tile = s0 >> 6;
    const int thalf = s0 & 32;                 // row offset within kv tile

    f32x4 acc[2][3];
    #pragma unroll
    for (int i = 0; i < 2; i++)
        #pragma unroll
        for (int j = 0; j < 3; j++)
            #pragma unroll
            for (int r = 0; r < 4; r++) acc[i][j][r] = 0.f;

    auto loadW = [&](int kt, short8 (&wh)[2][3], short8 (&wl)[2][3]) {
        #pragma unroll
        for (int ks = 0; ks < 2; ks++)
            #pragma unroll
            for (int ns = 0; ns < 3; ns++) {
                int rown = w * 48 + ns * 16 + (lane & 15);
                size_t kb = (size_t)kt * 8 + ks * 4 + (lane >> 4);
                wh[ks][ns] = *(const short8*)(WHp + kb * 1536 + rown * 8);
                wl[ks][ns] = *(const short8*)(WLp + kb * 1536 + rown * 8);
            }
    };

    short8 wAh[2][3], wAl[2][3], wBh[2][3], wBl[2][3];
    loadW(0, wAh, wAl);                        // prefetch kt=0 W frags

    // prologue: stage x tile for kt=0 into buf0 (512 float4 / 256 thr)
    {
        #pragma unroll
        for (int i = 0; i < 2; i++) {
            int c = tid + i * 256;
            int row = c >> 4, c16 = c & 15;
            float4 v = *(const float4*)(x + (size_t)(m0 + row) * DMODEL + c16 * 4);
            float vv[4] = {v.x, v.y, v.z, v.w};
            ushort4v hh, ll;
            #pragma unroll
            for (int j = 0; j < 4; j++) {
                unsigned short h1 = f2bf(vv[j]);
                hh[j] = h1; ll[j] = f2bf(vv[j] - bf2f(h1));
            }
            int ba = swz(row, c16 * 8);
            *(ushort4v*)(sm + ba) = hh;
            *(ushort4v*)(sm + 4096 + ba) = ll;
        }
        __syncthreads();
    }

    auto body = [&](int kt, short8 (&wh)[2][3], short8 (&wl)[2][3],
                    short8 (&nwh)[2][3], short8 (&nwl)[2][3]) {
        const int cur = kt & 1;
        unsigned char* xh = sm + cur * 8192;
        unsigned char* xl = xh + 4096;
        const bool last = (kt == 15);
        if (!last) loadW(kt + 1, nwh, nwl);    // prefetch next W (reg dbuf)
        // x loads for kt+1 (consumed after MFMA)
        float4 xn[2];
        if (!last) {
            #pragma unroll
            for (int i = 0; i < 2; i++) {
                int c = tid + i * 256;
                int row = c >> 4, c16 = c & 15;
                xn[i] = *(const float4*)(x + (size_t)(m0 + row) * DMODEL + (kt + 1) * 64 + c16 * 4);
            }
        }
        // MFMA over current buffers (W already in registers)
        #pragma unroll
        for (int ks = 0; ks < 2; ks++) {
            short8 ah[2], al[2];
            #pragma unroll
            for (int ms = 0; ms < 2; ms++) {
                int rowm = ms * 16 + (lane & 15);
                int off  = ks * 64 + ((lane >> 4) << 4);
                ah[ms] = *(const short8*)(xh + swz(rowm, off));
                al[ms] = *(const short8*)(xl + swz(rowm, off));
            }
            #pragma unroll
            for (int ns = 0; ns < 3; ns++) {
                #pragma unroll
                for (int ms = 0; ms < 2; ms++) {
                    acc[ms][ns] = __builtin_amdgcn_mfma_f32_16x16x32_bf16(ah[ms], wh[ks][ns], acc[ms][ns], 0, 0, 0);
                    acc[ms][ns] = __builtin_amdgcn_mfma_f32_16x16x32_bf16(ah[ms], wl[ks][ns], acc[ms][ns], 0, 0, 0);
                    acc[ms][ns] = __builtin_amdgcn_mfma_f32_16x16x32_bf16(al[ms], wh[ks][ns], acc[ms][ns], 0, 0, 0);
                }
            }
        }
        // split next x tile into the other buffer
        if (!last) {
            unsigned char* nh = sm + (cur ^ 1) * 8192;
            unsigned char* nl = nh + 4096;
            #pragma unroll
            for (int i = 0; i < 2; i++) {
                int c = tid + i * 256;
                int row = c >> 4, c16 = c & 15;
                float vv[4] = {xn[i].x, xn[i].y, xn[i].z, xn[i].w};
                ushort4v hh, ll;
                #pragma unroll
                for (int j = 0; j < 4; j++) {
                    unsigned short h1 = f2bf(vv[j]);
                    hh[j] = h1; ll[j] = f2bf(vv[j] - bf2f(h1));
                }
                int ba = swz(row, c16 * 8);
                *(ushort4v*)(nh + ba) = hh;
                *(ushort4v*)(nl + ba) = ll;
            }
        }
        __syncthreads();
    };

    #pragma unroll
    for (int kt2 = 0; kt2 < 16; kt2 += 2) {
        body(kt2,     wAh, wAl, wBh, wBl);
        body(kt2 + 1, wBh, wBl, wAh, wAl);
    }

    // epilogue: C/D 16x16 layout: col = lane&15, row = (lane>>4)*4 + r
    // K/V written in attn FRAGMENT order (see R5 header).
    #pragma unroll
    for (int ms = 0; ms < 2; ms++) {
        #pragma unroll
        for (int ns = 0; ns < 3; ns++) {
            int c   = w * 48 + ns * 16 + (lane & 15);
            int mat = c >> 6;                 // 0=Q 1=K 2=V (uniform per w,ns)
            int dk  = c & 63;
            int rb  = ms * 16 + ((lane >> 4) << 2);
            const size_t tb = (size_t)(b * 64 + tile) * 16384;
            if (mat == 0) {                   // Q: plain [b][s][64], pre-scaled
                #pragma unroll
                for (int r = 0; r < 4; r++) {
                    float v = acc[ms][ns][r] * QSCALE;
                    size_t o = (size_t)(m0 + rb + r) * DHEAD + dk;
                    unsigned short hh = f2bf(v);
                    QH[o] = hh; QL[o] = f2bf(v - bf2f(hh));
                }
            } else if (mat == 1) {            // K frag: sub=row>>5, ks=dk>>4
                const int ks = dk >> 4, hj = (dk >> 3) & 1, j = dk & 7;
                #pragma unroll
                for (int r = 0; r < 4; r++) {
                    float v = acc[ms][ns][r];
                    int row = thalf + rb + r;
                    size_t o = tb + (size_t)(((row >> 5) * 4 + ks) * 512
                                 + (hj * 32 + (row & 31)) * 8 + j);
                    unsigned short hh = f2bf(v);
                    KV[o] = hh; KV[o + 4096] = f2bf(v - bf2f(hh));
                }
            } else {                          // V frag: dsub=dk>>5, ks=col>>4
                ushort4v h, l;
                #pragma unroll
                for (int r = 0; r < 4; r++) {
                    float v = acc[ms][ns][r];
                    unsigned short hh = f2bf(v);
                    h[r] = hh; l[r] = f2bf(v - bf2f(hh));
                }
                const int col = thalf + rb;   // 4-aligned kv position
                const int ks = col >> 4, hj = (col >> 3) & 1, jb = col & 4;
                size_t o = tb + 8192 + (size_t)((((dk >> 5) * 4 + ks) * 512
                             + (hj * 32 + (dk & 31)) * 8 + jb));
                *(ushort4v*)(KV + o) = h;
                *(ushort4v*)(KV + o + 4096) = l;
            }
        }
    }
}

// ---------------------------------------------------------------- kernel 2 --
// Flash chunk, NO LDS: 1 wave per block = 32 q rows; KVB=64; frags loaded
// global->reg coalesced; K frags register-double-buffered (prefetch t+1).
// Swapped QK^T: sacc = S^T (col=lane&31 = q, rows = kv). Scalar m/l per lane.
__global__ __launch_bounds__(64, 2)
void attn_kernel(const unsigned short* __restrict__ QH, const unsigned short* __restrict__ QL,
                 const unsigned short* __restrict__ KV,
                 float* __restrict__ OP, float* __restrict__ ML,
                 float* __restrict__ out)
{
    const int lane = threadIdx.x;              // 0..63
    const int hi   = lane >> 5;
    const int b    = blockIdx.x & 7;           // batch == XCD slot: KV L2-local
    const int idx  = (int)(blockIdx.x >> 3);   // 0..319
    const int w    = idx & 3;                  // q sub-block within QB=128
    const int c    = 79 - (idx >> 2);          // big chunks first
    int qb, ch;
    if      (c < 8)  { qb = c;                ch = 0; }
    else if (c < 24) { qb = 8 + ((c - 8) >> 1);  ch = (c - 8) & 1; }
    else if (c < 48) { qb = 16 + (c - 24) / 3;   ch = (c - 24) % 3; }
    else             { qb = 24 + ((c - 48) >> 2); ch = (c - 48) & 3; }
    const int nc   = (qb < 8) ? 1 : ((qb < 16) ? 2 : ((qb < 24) ? 3 : 4));
    const int q0   = qb * 128;
    const int qABase = q0 + w * 32;            // wave's lowest q row
    const int qi     = qABase + (lane & 31);   // this lane's q row
    const int t0   = ch * 16;
    const int tend = min(t0 + 16, ((qABase + 31) >> 6) + 1);  // per-wave diag

    // Q fragments (B-operand: col=q, k=hi*8+j), straight from global
    short8 qh[4], ql[4];
    {
        const size_t qrow = (size_t)(b * SEQ + qi) * DHEAD;
        #pragma unroll
        for (int ks = 0; ks < 4; ks++) {
            int off = ks * 16 + hi * 8;
            qh[ks] = *(const short8*)(QH + qrow + off);
            ql[ks] = *(const short8*)(QL + qrow + off);
        }
    }

    f32x16 oacc[2];                            // O^T: col=q, rows=d (+32*dsub)
    #pragma unroll
    for (int r = 0; r < 16; r++) { oacc[0][r] = 0.f; oacc[1][r] = 0.f; }
    float m_s = M_INIT, l_s = 0.f;

    auto loadK = [&](int t, short8 (&kh)[2][4], short8 (&kl)[2][4]) {
        const unsigned short* KF = KV + (size_t)(b * 64 + t) * 16384 + lane * 8;
        #pragma unroll
        for (int sub = 0; sub < 2; sub++)
            #pragma unroll
            for (int ks = 0; ks < 4; ks++) {
                kh[sub][ks] = *(const short8*)(KF + (sub * 4 + ks) * 512);
                kl[sub][ks] = *(const short8*)(KF + 4096 + (sub * 4 + ks) * 512);
            }
    };

    auto step = [&](int t, short8 (&kh)[2][4], short8 (&kl)[2][4],
                    short8 (&nkh)[2][4], short8 (&nkl)[2][4]) {
        if (t + 1 < tend) loadK(t + 1, nkh, nkl);   // prefetch next K tile
        const int kv0 = t * 64;
        const unsigned short* KF = KV + (size_t)(b * 64 + t) * 16384 + lane * 8;

        // ---- S^T = K Q^T ----
        f32x16 sacc[2];
        #pragma unroll
        for (int r = 0; r < 16; r++) { sacc[0][r] = 0.f; sacc[1][r] = 0.f; }
        #pragma unroll
        for (int sub = 0; sub < 2; sub++) {
            #pragma unroll
            for (int ks = 0; ks < 4; ks++) {
                sacc[sub] = __builtin_amdgcn_mfma_f32_32x32x16_bf16(kh[sub][ks], qh[ks], sacc[sub], 0, 0, 0);
                sacc[sub] = __builtin_amdgcn_mfma_f32_32x32x16_bf16(kh[sub][ks], ql[ks], sacc[sub], 0, 0, 0);
                sacc[sub] = __builtin_amdgcn_mfma_f32_32x32x16_bf16(kl[sub][ks], qh[ks], sacc[sub], 0, 0, 0);
            }
        }

        // issue V-hi loads now; latency hides under mask+softmax VALU
        short8 vh[2][4];
        #pragma unroll
        for (int dsub = 0; dsub < 2; dsub++)
            #pragma unroll
            for (int ks = 0; ks < 4; ks++)
                vh[dsub][ks] = *(const short8*)(KF + 8192 + (dsub * 4 + ks) * 512);

        // ---- causal mask (finite sentinel) ----
        if (kv0 + 63 > qABase) {
            #pragma unroll
            for (int sub = 0; sub < 2; sub++)
                #pragma unroll
                for (int r = 0; r < 16; r++) {
                    int kvg = kv0 + sub * 32 + (r & 3) + 8 * (r >> 2) + 4 * hi;
                    if (kvg > qi) sacc[sub][r] = MASK_S;
                }
        }

        // ---- in-register online softmax (per-lane scalars) ----
        float vm = sacc[0][0];
        #pragma unroll
        for (int sub = 0; sub < 2; sub++)
            #pragma unroll
            for (int r = 0; r < 16; r++) vm = fmaxf(vm, sacc[sub][r]);
        vm = fmaxf(vm, __shfl_xor(vm, 32));
        const float mnew = fmaxf(m_s, vm);
        const float alff = __builtin_amdgcn_exp2f(m_s - mnew);
        m_s = mnew;
        float rs = 0.f;
        #pragma unroll
        for (int sub = 0; sub < 2; sub++)
            #pragma unroll
            for (int r = 0; r < 16; r++) {
                float p = __builtin_amdgcn_exp2f(sacc[sub][r] - mnew);
                sacc[sub][r] = p;
                rs += p;
            }
        rs += __shfl_xor(rs, 32);
        l_s = l_s * alff + rs;
        #pragma unroll
        for (int r = 0; r < 16; r++) { oacc[0][r] *= alff; oacc[1][r] *= alff; }

        // ---- P -> bf16 hi/lo frags + PV (O^T += V^T P^T) ----
        #pragma unroll
        for (int ks = 0; ks < 4; ks++) {
            const int sub = ks >> 1, rb = (ks & 1) * 8;
            float v0 = sacc[sub][rb + 0], v1 = sacc[sub][rb + 1];
            float v2 = sacc[sub][rb + 2], v3 = sacc[sub][rb + 3];
            float v4 = sacc[sub][rb + 4], v5 = sacc[sub][rb + 5];
            float v6 = sacc[sub][rb + 6], v7 = sacc[sub][rb + 7];
            unsigned Ah0 = cvtpk(v0, v1), Ah1 = cvtpk(v2, v3);
            unsigned Bh0 = cvtpk(v4, v5), Bh1 = cvtpk(v6, v7);
            float l0 = v0 - asf(Ah0 << 16), l1 = v1 - asf(Ah0 & 0xffff0000u);
            float l2 = v2 - asf(Ah1 << 16), l3 = v3 - asf(Ah1 & 0xffff0000u);
            float l4 = v4 - asf(Bh0 << 16), l5 = v5 - asf(Bh0 & 0xffff0000u);
            float l6 = v6 - asf(Bh1 << 16), l7 = v7 - asf(Bh1 & 0xffff0000u);
            unsigned Al0 = cvtpk(l0, l1), Al1 = cvtpk(l2, l3);
            unsigned Bl0 = cvtpk(l4, l5), Bl1 = cvtpk(l6, l7);
            // exchange: hi=0 sends B(kv8-11), gets partner A(kv4-7); hi=1 opp.
            unsigned eh0 = __shfl_xor(hi ? Ah0 : Bh0, 32);
            unsigned eh1 = __shfl_xor(hi ? Ah1 : Bh1, 32);
            unsigned el0 = __shfl_xor(hi ? Al0 : Bl0, 32);
            unsigned el1 = __shfl_xor(hi ? Al1 : Bl1, 32);
            short8 PH = hi ? mk8(eh0, eh1, Bh0, Bh1) : mk8(Ah0, Ah1, eh0, eh1);
            short8 PL = hi ? mk8(el0, el1, Bl0, Bl1) : mk8(Al0, Al1, el0, el1);
            #pragma unroll
            for (int dsub = 0; dsub < 2; dsub++) {
                short8 vl = *(const short8*)(KF + 12288 + (dsub * 4 + ks) * 512);
                oacc[dsub] = __builtin_amdgcn_mfma_f32_32x32x16_bf16(vh[dsub][ks], PH, oacc[dsub], 0, 0, 0);
                oacc[dsub] = __builtin_amdgcn_mfma_f32_32x32x16_bf16(vh[dsub][ks], PL, oacc[dsub], 0, 0, 0);
                oacc[dsub] = __builtin_amdgcn_mfma_f32_32x32x16_bf16(vl, PH, oacc[dsub], 0, 0, 0);
            }
        }
    };

    // 2-state rotation, static register indexing
    short8 kAh[2][4], kAl[2][4], kBh[2][4], kBl[2][4];
    int t = t0;
    loadK(t, kAh, kAl);
    while (true) {
        step(t, kAh, kAl, kBh, kBl);
        ++t; if (t >= tend) break;
        step(t, kBh, kBl, kAh, kAl);
        ++t; if (t >= tend) break;
    }

    // ---- epilogue: O^T cols=q, rows d = dsub*32 + 8*rg + 4*hi + (r&3) ----
    if (nc == 1) {
        const float inv = 1.f / l_s;
        float* orow = out + (size_t)(b * SEQ + qi) * DHEAD;
        #pragma unroll
        for (int dsub = 0; dsub < 2; dsub++)
            #pragma unroll
            for (int rg = 0; rg < 4; rg++) {
                f32x4 v;
                #pragma unroll
                for (int j = 0; j < 4; j++) v[j] = oacc[dsub][rg * 4 + j] * inv;
                *(f32x4*)(orow + dsub * 32 + rg * 8 + hi * 4) = v;
            }
    } else {
        const size_t cbase = (size_t)((b * 32 + qb) * 4 + ch);
        float* orow = OP + cbase * 8192 + (size_t)(w * 32 + (lane & 31)) * 64;
        #pragma unroll
        for (int dsub = 0; dsub < 2; dsub++)
            #pragma unroll
            for (int rg = 0; rg < 4; rg++) {
                f32x4 v;
                #pragma unroll
                for (int j = 0; j < 4; j++) v[j] = oacc[dsub][rg * 4 + j];
                *(f32x4*)(orow + dsub * 32 + rg * 8 + hi * 4) = v;
            }
        if (hi == 0) {
            size_t o = cbase * 256 + (size_t)(w * 32 + lane) * 2;
            ML[o] = m_s; ML[o + 1] = l_s;
        }
    }
}

// ---------------------------------------------------------------- kernel 3 --
// Merge chunks for qb >= 8 (2..4 chunks). grid 8*24, 256 thr. exp2 domain.
__global__ __launch_bounds__(256, 4)
void combine_kernel(const float* __restrict__ OP, const float* __restrict__ ML,
                    float* __restrict__ out)
{
    const int b   = blockIdx.x & 7;
    const int qb  = 8 + (int)(blockIdx.x >> 3);
    const int nc  = (qb < 16) ? 2 : ((qb < 24) ? 3 : 4);
    const int qlo = threadIdx.x >> 1;          // 0..127
    const int d0  = (threadIdx.x & 1) * 32;
    const size_t cbase = (size_t)(b * 32 + qb) * 4;

    float mv[4], lv[4];
    float M = MASK_S;
    #pragma unroll
    for (int ch = 0; ch < 4; ch++) if (ch < nc) {
        mv[ch] = ML[(cbase + ch) * 256 + qlo * 2];
        lv[ch] = ML[(cbase + ch) * 256 + qlo * 2 + 1];
        M = fmaxf(M, mv[ch]);
    }
    float L = 0.f, sc[4];
    #pragma unroll
    for (int ch = 0; ch < 4; ch++) if (ch < nc) {
        sc[ch] = __builtin_amdgcn_exp2f(mv[ch] - M);
        L += lv[ch] * sc[ch];
    }
    const float inv = 1.f / L;

    f32x4 acc[8];
    #pragma unroll
    for (int j = 0; j < 8; j++) { acc[j][0] = 0.f; acc[j][1] = 0.f; acc[j][2] = 0.f; acc[j][3] = 0.f; }
    #pragma unroll
    for (int ch = 0; ch < 4; ch++) if (ch < nc) {
        const float* bp = OP + (cbase + ch) * 8192 + (size_t)qlo * 64 + d0;
        #pragma unroll
        for (int j = 0; j < 8; j++) acc[j] += *(const f32x4*)(bp + j * 4) * sc[ch];
    }
    float* ob = out + (size_t)(b * SEQ + qb * 128 + qlo) * 64 + d0;
    #pragma unroll
    for (int j = 0; j < 8; j++) *(f32x4*)(ob + j * 4) = acc[j] * inv;
}

// ------------------------------------------------------------------- launch --
extern "C" void kernel_launch(void* const* d_in, const int* in_sizes, int n_in,
                              void* d_out, int out_size, void* d_ws, size_t ws_size,
                              hipStream_t stream)
{
    const float* x  = (const float*)d_in[0];
    const float* wQ = (const float*)d_in[1];
    const float* wK = (const float*)d_in[2];
    const float* wV = (const float*)d_in[3];
    float* out = (float*)d_out;

    // workspace: W 0.75MB + Q 8.4MB + KV 16.8MB + OP 33.5MB + ML 1MB ~= 60.5MB
    unsigned short* p   = (unsigned short*)d_ws;
    unsigned short* WHp = p; p += 192 * 1024;
    unsigned short* WLp = p; p += 192 * 1024;
    unsigned short* QHp = p; p += 8 * 4096 * 64;
    unsigned short* QLp = p; p += 8 * 4096 * 64;
    unsigned short* KVp = p; p += (size_t)8 * 64 * 16384;
    float* fp = (float*)p;
    float* OP = fp; fp += (size_t)8 * 32 * 4 * 8192;   // partial O
    float* ML = fp; fp += (size_t)8 * 32 * 4 * 256;    // (m,l)

    splitw_kernel<<<dim3(192), dim3(256), 0, stream>>>(wQ, wK, wV, WHp, WLp);
    proj_kernel<<<dim3(1024), dim3(256), 0, stream>>>(x, WHp, WLp, QHp, QLp, KVp);
    attn_kernel<<<dim3(2560), dim3(64), 0, stream>>>(QHp, QLp, KVp, OP, ML, out);
    combine_kernel<<<dim3(192), dim3(256), 0, stream>>>(OP, ML, out);
}